// Round 6
// baseline (56.041 us; speedup 1.0000x reference)
//
#include <hip/hip_runtime.h>
#include <hip/hip_fp16.h>

#define T_DIM   1500
#define ROW_F   32000              // floats per row
#define TOT_F   48000000L          // T_DIM * ROW_F
#define START_T 9                  // max(U-1,1), U=10
#define NB      16384              // N * ctc_beam
#define BLOCK   512
#define CPT     32                 // NB/BLOCK
#define NPAIR   16                 // CPT/2 packed candidate pairs
#define ROWS    6                  // 250*6 = 1500 exactly
#define NCHUNK  250
#define NEGBIG  -3.0e38f
#define EOS_ID  1
#define LN2     0.69314718055994531f
#define L2E     1.44269504088896341f

#if __has_builtin(__builtin_amdgcn_exp2f)
__device__ __forceinline__ float fexp2(float x) { return __builtin_amdgcn_exp2f(x); }
#else
__device__ __forceinline__ float fexp2(float x) { return __expf(x * LN2); }
#endif
#if __has_builtin(__builtin_amdgcn_logf)
__device__ __forceinline__ float flog2(float x) { return __builtin_amdgcn_logf(x); }
#else
__device__ __forceinline__ float flog2(float x) { return __logf(x) * L2E; }
#endif

// lgkmcnt(0)-only barrier: orders LDS ops; in-flight global_load_lds DMAs
// (vmcnt) deliberately stay in flight across it.
#define WG_BARRIER() do { \
  asm volatile("s_waitcnt lgkmcnt(0)" ::: "memory"); \
  __builtin_amdgcn_s_barrier(); \
  asm volatile("" ::: "memory"); \
} while (0)

typedef __attribute__((address_space(1))) void* as1_ptr;
typedef __attribute__((address_space(3))) void* as3_ptr;

// K1: one workgroup per 6-row chunk. Rows stream via global_load_lds DMA
// (8 slices x 16KB into a 2x16KB LDS ping-pong, 2-slice lookahead,
// counted vmcnt(2) -- never drained to 0 in the loop). Each wave DMAs and
// reads ONLY its own granules -> no barriers on the B buffers. Slice
// processing converts f32->fp16 probabilities px=exp2(logit*L2E) into the
// double-buffered gather row A (one lgkm-only barrier per row). No register
// staging arrays -> ~90 VGPR, no spill.
__global__ __launch_bounds__(BLOCK, 2)
void ctc_k1(const float* __restrict__ P, const int* __restrict__ cidx,
            float* __restrict__ Lws, float* __restrict__ Sblank)
{
  __shared__ __align__(16) __half Ah[64000];     // 2 x 32000 fp16 px rows (128000 B)
  __shared__ __align__(16) float  Bs[2][4096];   // DMA slice ping-pong (32768 B)
  __shared__ float red[2][12];                   // 8 wave sums + blank logit (x L2E)
  const int tid = threadIdx.x;
  const int w   = tid >> 6;       // wave 0..7
  const int l   = tid & 63;       // lane
  const int q   = blockIdx.x;
  const int t0  = q * ROWS;

  // candidate indices packed as two u16 A-byte-offsets per VGPR (c*2 < 64000)
  unsigned cidp[NPAIR];
  float acc[CPT];
#pragma unroll
  for (int j = 0; j < NPAIR; ++j) {
    unsigned c0 = (unsigned)cidx[(2*j  )*BLOCK + tid] * 2u;
    unsigned c1 = (unsigned)cidx[(2*j+1)*BLOCK + tid] * 2u;
    cidp[j] = c0 | (c1 << 16);
    acc[2*j] = 0.f; acc[2*j+1] = 0.f;
  }

  float blankv  = 0.f;   // raw f32 blank logit of the row being staged
  float Blocal2 = 0.f;   // chunk-local blank prefix, log2 units

  // issue one slice's 2 granules for this wave: global slice index g (0..47)
  auto ISSUE = [&](int g) {
    const int rr = g >> 3, ss = g & 7;
    long f0 = (long)(t0 + rr) * ROW_F + (ss << 12) + (w << 9) + (l << 2);
    long f1 = f0 + 256;
    // clamp pad-granule reads of the global last row (stay in bounds)
    f0 = (f0 > TOT_F - 4) ? (TOT_F - 4) : f0;
    f1 = (f1 > TOT_F - 4) ? (TOT_F - 4) : f1;
    float* b0 = &Bs[g & 1][(w << 9)];
    __builtin_amdgcn_global_load_lds((as1_ptr)(P + f0), (as3_ptr)(b0      ), 16, 0, 0);
    __builtin_amdgcn_global_load_lds((as1_ptr)(P + f1), (as3_ptr)(b0 + 256), 16, 0, 0);
  };

  // stage one row (8 slices) into A half 'nb'; DMA lookahead crosses rows.
  auto STAGE_ROW = [&](int gbase, int nb, bool LASTROW) {
    float psum = 0.f;
#pragma unroll
    for (int ss = 0; ss < 8; ++ss) {
      const int g = gbase + ss;
      if (LASTROW && ss == 7) { asm volatile("s_waitcnt vmcnt(0)" ::: "memory"); }
      else                    { asm volatile("s_waitcnt vmcnt(2)" ::: "memory"); }
      const int len = (ss == 7) ? 3328 : 4096;           // last slice is partial
      const int rem = len - (w << 9);
      const int nj  = (rem >= 512) ? 8 : (rem > 0 ? (rem >> 6) : 0);
      float x[8];
      const float* Bsl = &Bs[g & 1][(w << 9) + l];
#pragma unroll
      for (int j = 0; j < 8; ++j) if (j < nj) x[j] = Bsl[j << 6];
      asm volatile("s_waitcnt lgkmcnt(0)" ::: "memory"); // reads done before overwrite
      if (g + 2 < 48) ISSUE(g + 2);
      __half* Adst = Ah + nb * ROW_F + (ss << 12) + (w << 9) + l;
#pragma unroll
      for (int j = 0; j < 8; ++j) if (j < nj) {
        float px = fexp2(x[j] * L2E);
        psum += px;                                      // f32 row LSE sum
        Adst[j << 6] = __float2half_rn(px);
        if (ss == 7 && j == 3 && tid == 447) blankv = x[j];  // element 31999
      }
    }
#pragma unroll
    for (int d = 1; d < 64; d <<= 1) psum += __shfl_xor(psum, d);
    if (l == 0) red[nb][w] = psum;
    if (tid == 447) red[nb][8] = blankv * L2E;           // exact f32 blank logit
  };

  auto GATHER = [&](int r) {
    const int b = r & 1;
    float sum = red[b][0];
#pragma unroll
    for (int ww = 1; ww < 8; ++ww) sum += red[b][ww];
    const float lse2 = flog2(sum);
    if (t0 + r >= START_T) {
      const float sc = fexp2(Blocal2 - lse2);   // wave-uniform scale, no underflow in-chunk
      const char* rb = (const char*)Ah + b * 64000;
#pragma unroll
      for (int j = 0; j < NPAIR; ++j) {
        unsigned pk = cidp[j];
        float p0 = __half2float(*(const __half*)(rb + (pk & 0xffffu)));
        float p1 = __half2float(*(const __half*)(rb + (pk >> 16)));
        acc[2*j]   = fmaf(sc, p0, acc[2*j]);
        acc[2*j+1] = fmaf(sc, p1, acc[2*j+1]);
      }
    }
    Blocal2 += red[b][8] - lse2;
  };

  // prologue: start the DMA stream, stage row 0 into A half 0
  ISSUE(0); ISSUE(1);
  STAGE_ROW(0, 0, false);
  WG_BARRIER();

  for (int r = 0; r < 5; ++r) {
    GATHER(r);                                   // row r from A[r&1] (ready)
    STAGE_ROW((r + 1) * 8, (r + 1) & 1, r == 4); // row r+1 -> A[(r+1)&1]
    WG_BARRIER();
  }
  GATHER(5);

#pragma unroll
  for (int k = 0; k < CPT; ++k) {
    float L = (acc[k] > 0.f) ? flog2(acc[k]) * LN2 : NEGBIG;   // nats
    Lws[(long)q*NB + k*BLOCK + tid] = L;
  }
  if (tid == 0) Sblank[q] = Blocal2 * LN2;
}

#define K3_BLOCK 256

// K3: 256 blocks x 64 candidates, 4 waves split the 250 chunks 4-way.
// Block-scan chunk blank-sums -> base offsets, online logsumexp per part,
// LDS combine, EOS override.
__global__ __launch_bounds__(K3_BLOCK)
void ctc_k3(const float* __restrict__ Lws, const float* __restrict__ Sblank,
            const int* __restrict__ cidx, float* __restrict__ out, int nchunk)
{
  __shared__ float base[258];
  __shared__ float wsum[4];
  __shared__ float pm[4][64], pv[4][64];
  const int tid = threadIdx.x;

  // inclusive block scan of Sblank (nchunk <= 250 < 256)
  float orig = (tid < nchunk) ? Sblank[tid] : 0.f;
  float x = orig;
#pragma unroll
  for (int d = 1; d < 64; d <<= 1) {
    float y = __shfl_up(x, d);
    if ((tid & 63) >= d) x += y;
  }
  if ((tid & 63) == 63) wsum[tid >> 6] = x;
  __syncthreads();
  {
    const int ww = tid >> 6;
    float pre = 0.f;
    if (ww > 0) pre += wsum[0];
    if (ww > 1) pre += wsum[1];
    if (ww > 2) pre += wsum[2];
    x += pre;
  }
  if (tid < nchunk)      base[tid] = x - orig;   // exclusive prefix: gb[chunk_start-1]
  if (tid == nchunk - 1) base[nchunk] = x;       // total = gb[T-1]
  __syncthreads();

  const int c = tid & 63;          // candidate lane
  const int p = tid >> 6;          // chunk part 0..3
  const int i = blockIdx.x * 64 + c;
  const int c0 = p * 63;
  int c1 = c0 + 63; if (c1 > nchunk) c1 = nchunk;

  float mm = NEGBIG, ssum = 0.f;
#pragma unroll 8
  for (int q2 = c0; q2 < c1; ++q2) {
    float L = Lws[(long)q2*NB + i] + base[q2];
    float nm = fmaxf(mm, L);
    ssum = ssum*__expf(mm - nm) + __expf(L - nm);
    mm = nm;
  }
  pm[p][c] = mm; pv[p][c] = ssum;
  __syncthreads();
  if (p == 0) {
#pragma unroll
    for (int pp = 1; pp < 4; ++pp) {
      float om = pm[pp][c], os = pv[pp][c];
      float nm = fmaxf(mm, om);
      ssum = ssum*__expf(mm - nm) + os*__expf(om - nm);
      mm = nm;
    }
    float sc = mm + __logf(ssum);
    out[i] = (cidx[i] == EOS_ID) ? base[nchunk] : sc;
  }
}

extern "C" void kernel_launch(void* const* d_in, const int* in_sizes, int n_in,
                              void* d_out, int out_size, void* d_ws, size_t ws_size,
                              hipStream_t stream)
{
  const float* P    = (const float*)d_in[0];
  const int*   cidx = (const int*)d_in[2];
  float*       out  = (float*)d_out;

  float* Lws    = (float*)d_ws;                 // NCHUNK*NB floats = 16.4 MB
  float* Sblank = Lws + (long)NCHUNK * NB;

  ctc_k1<<<dim3(NCHUNK), dim3(BLOCK), 0, stream>>>(P, cidx, Lws, Sblank);
  ctc_k3<<<dim3(NB / 64), dim3(K3_BLOCK), 0, stream>>>(Lws, Sblank, cidx, out, NCHUNK);
}